// Round 1
// 299.292 us; speedup vs baseline: 1.1349x; 1.1349x over previous
//
#include <hip/hip_runtime.h>
#include <math.h>

// DeepMMD, round 3: joint symmetric 8192x8192 pass, 128x128 tiles (2080 blocks).
//  - org-space dot: fp16 hi/lo split (3 products) on v_mfma_f32_32x32x16_f16
//  - feature distance: exact fp32 sum of squared diffs, packed float2 (v_pk_fma_f32)
//  - epilogue: single full-tile pass, all 4 waves eval their own accs in MFMA
//    C-layout against an LDS-resident 128x128 e2 tile (3 barriers, was ~14)
//  - reductions: row/col sums -> fp32 atomics on D8[8192]; Sxx/Syy/Sxy/trace fp64 atomics

#define N_S 4096
#define LOG2E 1.4426950408889634

typedef _Float16 v8h __attribute__((ext_vector_type(8)));
typedef float v16f __attribute__((ext_vector_type(16)));
typedef float v2f __attribute__((ext_vector_type(2)));

union U16 { uint4 u; v8h h; };

// ---------------- MLP (fp64 internals) -> featsT[52][8192] fp32, wOrg[8192] ----------------
__global__ __launch_bounds__(64)
void mlp_kernel(const float* __restrict__ X, const float* __restrict__ Y,
                const float* __restrict__ W1, const float* __restrict__ b1,
                const float* __restrict__ W2, const float* __restrict__ b2,
                const float* __restrict__ W3, const float* __restrict__ b3,
                const float* __restrict__ W4, const float* __restrict__ b4,
                const float* __restrict__ sq,
                float* __restrict__ featsT, float* __restrict__ wOrg)
{
    __shared__ double sW1[2560];
    __shared__ double sW2[100], sW3[100], sW4[500];
    __shared__ double sb1[10], sb2[10], sb3[10], sb4[50];
    int tid = threadIdx.x;
    for (int i = tid; i < 2560; i += 64) sW1[i] = (double)W1[i];
    for (int i = tid; i < 100; i += 64) { sW2[i] = (double)W2[i]; sW3[i] = (double)W3[i]; }
    for (int i = tid; i < 500; i += 64) sW4[i] = (double)W4[i];
    if (tid < 10) { sb1[tid] = (double)b1[tid]; sb2[tid] = (double)b2[tid]; sb3[tid] = (double)b3[tid]; }
    for (int i = tid; i < 50; i += 64) sb4[i] = (double)b4[i];
    __syncthreads();

    int r = blockIdx.x * 64 + tid;
    const float* xr = (r < N_S) ? (X + (size_t)r * 256) : (Y + (size_t)(r - N_S) * 256);

    double z[10];
#pragma unroll
    for (int j = 0; j < 10; ++j) z[j] = sb1[j];
    double nrm = 0.0;
    for (int k4 = 0; k4 < 256; k4 += 4) {
        float4 xv4 = *(const float4*)(xr + k4);
        double xv[4] = {(double)xv4.x, (double)xv4.y, (double)xv4.z, (double)xv4.w};
#pragma unroll
        for (int u = 0; u < 4; ++u) {
            nrm += xv[u] * xv[u];
#pragma unroll
            for (int j = 0; j < 10; ++j) z[j] += xv[u] * sW1[(k4 + u) * 10 + j];
        }
    }
#pragma unroll
    for (int j = 0; j < 10; ++j) z[j] = fmax(z[j], 0.0) + log1p(exp(-fabs(z[j])));

    double z2[10];
#pragma unroll
    for (int j = 0; j < 10; ++j) z2[j] = sb2[j];
#pragma unroll
    for (int k = 0; k < 10; ++k)
#pragma unroll
        for (int j = 0; j < 10; ++j) z2[j] += z[k] * sW2[k * 10 + j];
#pragma unroll
    for (int j = 0; j < 10; ++j) z2[j] = fmax(z2[j], 0.0) + log1p(exp(-fabs(z2[j])));

    double z3[10];
#pragma unroll
    for (int j = 0; j < 10; ++j) z3[j] = sb3[j];
#pragma unroll
    for (int k = 0; k < 10; ++k)
#pragma unroll
        for (int j = 0; j < 10; ++j) z3[j] += z2[k] * sW3[k * 10 + j];
#pragma unroll
    for (int j = 0; j < 10; ++j) z3[j] = fmax(z3[j], 0.0) + log1p(exp(-fabs(z3[j])));

    for (int j = 0; j < 50; ++j) {
        double f = sb4[j];
#pragma unroll
        for (int k = 0; k < 10; ++k) f += z3[k] * sW4[k * 50 + j];
        featsT[(size_t)j * 8192 + r] = (float)f;   // coalesced across lanes
    }
    featsT[(size_t)50 * 8192 + r] = 0.0f;          // zero pad dims
    featsT[(size_t)51 * 8192 + r] = 0.0f;

    double sqv = (double)sq[0];
    double co = LOG2E / (sqv * sqv);
    wOrg[r] = (float)exp2(-nrm * co);
}

// ---------------- helpers ----------------
__device__ __forceinline__ v8h ldfrag(const uint4* buf, int s, int g) {
    U16 t; t.u = buf[s * 8 + (g ^ (s & 7))];
    return t.h;
}

__device__ __forceinline__ void cvt_split(float4 f0, float4 f1, uint4* hi, uint4* lo) {
    U16 H, L;
    float fv[8] = {f0.x, f0.y, f0.z, f0.w, f1.x, f1.y, f1.z, f1.w};
#pragma unroll
    for (int u = 0; u < 8; ++u) {
        _Float16 h = (_Float16)fv[u];
        H.h[u] = h;
        L.h[u] = (_Float16)(fv[u] - (float)h);
    }
    *hi = H.u; *lo = L.u;
}

// ---------------- joint pairwise pass ----------------
__global__ __launch_bounds__(256, 2)
void pair_kernel(const float* __restrict__ X, const float* __restrict__ Y,
                 const float* __restrict__ featsT, const float* __restrict__ wOrg,
                 const float* __restrict__ ep, const float* __restrict__ sq,
                 const float* __restrict__ sph,
                 float* __restrict__ D8, double* __restrict__ S)
{
    // LDS union: phase F: FA[52][132] (27456) + FB (27456) = 54912
    //            phase A: Ahi/Alo/Bhi/Blo uint4[1024] each = 65536
    //            epilogue: E2[128][128] f32 = 65536; dred 8 f64 (overlaid after sync)
    __shared__ __align__(16) char smem[65536];

    int tid = threadIdx.x;
    int lane = tid & 63, w = tid >> 6, wr = w >> 1, wc = w & 1;
    int tx = tid & 15, ty = tid >> 4;

    // upper-triangle tile decode
    int L = blockIdx.x, it = 0, span = 64;
    while (L >= span) { L -= span; --span; ++it; }
    int jt = it + L;

    bool sameHalf = (jt < 32) || (it >= 32);
    bool isDiag = (it == jt);
    bool isTrace = (jt == it + 32);
    int region = (jt < 32) ? 0 : ((it >= 32) ? 1 : 2);
    float sgn = sameHalf ? 1.0f : -1.0f;
    int i0 = it * 128, j0 = jt * 128;
    const float* aorg = (it < 32) ? X + (size_t)i0 * 256 : Y + (size_t)(i0 - N_S) * 256;
    const float* borg = (jt < 32) ? X + (size_t)j0 * 256 : Y + (size_t)(j0 - N_S) * 256;

    double epd = (double)ep[0];
    double eps = 1.0 / (1.0 + exp(-epd));
    double sqv = (double)sq[0], spv = (double)sph[0];
    float cf = (float)(LOG2E / (spv * spv));            // feature exponent scale
    float twoco = (float)(2.0 * LOG2E / (sqv * sqv));   // org dot exponent scale
    float epsv = (float)eps, ome = (float)(1.0 - eps);

    // ---- phase F: exact fp32 feature distances (8x8 per thread, packed f32) ----
    float* FA = (float*)smem;
    float* FB = (float*)(smem + 27456);
    for (int idx = tid; idx < 1600; idx += 256) {    // 50 rows x 32 float4
        int k = idx >> 5, cg = (idx & 31) * 4;
        *(float4*)&FA[k * 132 + cg] = *(const float4*)&featsT[(size_t)k * 8192 + i0 + cg];
        *(float4*)&FB[k * 132 + cg] = *(const float4*)&featsT[(size_t)k * 8192 + j0 + cg];
    }
    __syncthreads();

    v2f da2[8][4];
#pragma unroll
    for (int i = 0; i < 8; ++i)
#pragma unroll
        for (int j = 0; j < 4; ++j) { da2[i][j][0] = 0.0f; da2[i][j][1] = 0.0f; }

    int r0 = ty * 8, c0 = tx * 8;
    for (int k = 0; k < 50; ++k) {
        float4 a0 = *(const float4*)&FA[k * 132 + r0];
        float4 a1 = *(const float4*)&FA[k * 132 + r0 + 4];
        float4 b0 = *(const float4*)&FB[k * 132 + c0];
        float4 b1 = *(const float4*)&FB[k * 132 + c0 + 4];
        float av[8] = {a0.x, a0.y, a0.z, a0.w, a1.x, a1.y, a1.z, a1.w};
        v2f bv[4];
        bv[0][0] = b0.x; bv[0][1] = b0.y; bv[1][0] = b0.z; bv[1][1] = b0.w;
        bv[2][0] = b1.x; bv[2][1] = b1.y; bv[3][0] = b1.z; bv[3][1] = b1.w;
#pragma unroll
        for (int i = 0; i < 8; ++i) {
            v2f ai; ai[0] = av[i]; ai[1] = av[i];
#pragma unroll
            for (int j = 0; j < 4; ++j) {
                v2f t = ai - bv[j];          // v_pk_add_f32 (neg)
                da2[i][j] += t * t;          // v_pk_fma_f32
            }
        }
    }
    // d -> e2 (kept in registers through phase A)
#pragma unroll
    for (int i = 0; i < 8; ++i)
#pragma unroll
        for (int j = 0; j < 4; ++j) {
            da2[i][j][0] = exp2f(-da2[i][j][0] * cf);
            da2[i][j][1] = exp2f(-da2[i][j][1] * cf);
        }
    __syncthreads();   // FA/FB dead

    // ---- phase A: fp16-split MFMA org dot ----
    uint4* Ahi = (uint4*)smem;
    uint4* Alo = Ahi + 1024;
    uint4* Bhi = Ahi + 2048;
    uint4* Blo = Ahi + 3072;

    v16f acc00{}, acc01{}, acc10{}, acc11{};
    int rs0 = wr * 64 + (lane & 31), rs1 = rs0 + 32;
    int cs0 = wc * 64 + (lane & 31), cs1 = cs0 + 32;

    for (int kb = 0; kb < 256; kb += 64) {
#pragma unroll
        for (int step = 0; step < 4; ++step) {
            int r = step * 32 + (tid >> 3), g8 = tid & 7;
            const float* pa = aorg + (size_t)r * 256 + kb + g8 * 8;
            const float* pb = borg + (size_t)r * 256 + kb + g8 * 8;
            float4 fa0 = *(const float4*)pa, fa1 = *(const float4*)(pa + 4);
            float4 fb0 = *(const float4*)pb, fb1 = *(const float4*)(pb + 4);
            uint4 hi, lo;
            int pg = r * 8 + (g8 ^ (r & 7));          // XOR swizzle, conflict-free b128
            cvt_split(fa0, fa1, &hi, &lo);
            Ahi[pg] = hi; Alo[pg] = lo;
            cvt_split(fb0, fb1, &hi, &lo);
            Bhi[pg] = hi; Blo[pg] = lo;
        }
        __syncthreads();
#pragma unroll
        for (int ks = 0; ks < 4; ++ks) {
            int g = ks * 2 + (lane >> 5);
            v8h ah0 = ldfrag(Ahi, rs0, g), ah1 = ldfrag(Ahi, rs1, g);
            v8h al0 = ldfrag(Alo, rs0, g), al1 = ldfrag(Alo, rs1, g);
            v8h bh0 = ldfrag(Bhi, cs0, g), bh1 = ldfrag(Bhi, cs1, g);
            v8h bl0 = ldfrag(Blo, cs0, g), bl1 = ldfrag(Blo, cs1, g);
            acc00 = __builtin_amdgcn_mfma_f32_32x32x16_f16(al0, bh0, acc00, 0, 0, 0);
            acc00 = __builtin_amdgcn_mfma_f32_32x32x16_f16(ah0, bl0, acc00, 0, 0, 0);
            acc00 = __builtin_amdgcn_mfma_f32_32x32x16_f16(ah0, bh0, acc00, 0, 0, 0);
            acc01 = __builtin_amdgcn_mfma_f32_32x32x16_f16(al0, bh1, acc01, 0, 0, 0);
            acc01 = __builtin_amdgcn_mfma_f32_32x32x16_f16(ah0, bl1, acc01, 0, 0, 0);
            acc01 = __builtin_amdgcn_mfma_f32_32x32x16_f16(ah0, bh1, acc01, 0, 0, 0);
            acc10 = __builtin_amdgcn_mfma_f32_32x32x16_f16(al1, bh0, acc10, 0, 0, 0);
            acc10 = __builtin_amdgcn_mfma_f32_32x32x16_f16(ah1, bl0, acc10, 0, 0, 0);
            acc10 = __builtin_amdgcn_mfma_f32_32x32x16_f16(ah1, bh0, acc10, 0, 0, 0);
            acc11 = __builtin_amdgcn_mfma_f32_32x32x16_f16(al1, bh1, acc11, 0, 0, 0);
            acc11 = __builtin_amdgcn_mfma_f32_32x32x16_f16(ah1, bl1, acc11, 0, 0, 0);
            acc11 = __builtin_amdgcn_mfma_f32_32x32x16_f16(ah1, bh1, acc11, 0, 0, 0);
        }
        __syncthreads();   // frag reads done before next staging overwrite
    }

    // ---- epilogue: single full-tile pass, all waves ----
    float* E2 = (float*)smem;

    // write e2 (thread-tile layout) into full 128x128 LDS tile
#pragma unroll
    for (int i = 0; i < 8; ++i) {
        float4 v0 = make_float4(da2[i][0][0], da2[i][0][1], da2[i][1][0], da2[i][1][1]);
        float4 v1 = make_float4(da2[i][2][0], da2[i][2][1], da2[i][3][0], da2[i][3][1]);
        *(float4*)&E2[(r0 + i) * 128 + c0] = v0;
        *(float4*)&E2[(r0 + i) * 128 + c0 + 4] = v1;
    }
    __syncthreads();

    // each wave evaluates its own 4 accs in MFMA C-layout
    double bsum = 0.0, trsum = 0.0;
    float colacc0 = 0.0f, colacc1 = 0.0f;
    int cl0 = wc * 64 + (lane & 31), cl1 = cl0 + 32;
    float wb0 = wOrg[j0 + cl0];
    float wb1 = wOrg[j0 + cl1];

    auto evalpair = [&](const v16f& aj0, const v16f& aj1, int rbase) {
#pragma unroll
        for (int reg = 0; reg < 16; ++reg) {
            int rl = rbase + 4 * (lane >> 5) + (reg & 3) + 8 * (reg >> 2);
            float wa = wOrg[i0 + rl];
            {
                float e2v = E2[rl * 128 + cl0];
                float kv = wa * wb0 * exp2f(aj0[reg] * twoco) * (ome * e2v + epsv);
                if (isDiag && rl == cl0) kv = 0.0f;
                if (isTrace && cl0 == rl) trsum += (double)kv;
                bsum += (double)kv;
                colacc0 += kv;
                E2[rl * 128 + cl0] = kv;
            }
            {
                float e2v = E2[rl * 128 + cl1];
                float kv = wa * wb1 * exp2f(aj1[reg] * twoco) * (ome * e2v + epsv);
                if (isDiag && rl == cl1) kv = 0.0f;
                if (isTrace && cl1 == rl) trsum += (double)kv;
                bsum += (double)kv;
                colacc1 += kv;
                E2[rl * 128 + cl1] = kv;
            }
        }
    };
    evalpair(acc00, acc01, wr * 64);
    evalpair(acc10, acc11, wr * 64 + 32);
    __syncthreads();

    // row sums: 2 threads per row, rotated start to spread banks
    {
        int row = tid >> 1, half = tid & 1;
        float s = 0.0f;
#pragma unroll
        for (int q = 0; q < 16; ++q) {
            int qq = (q + row) & 15;
            float4 v = *(const float4*)&E2[row * 128 + half * 64 + qq * 4];
            s += v.x + v.y + v.z + v.w;
        }
        s += __shfl_xor(s, 1);
        if (half == 0) atomicAdd(&D8[i0 + row], sgn * s);
    }

    // column sums (skip for diagonal tiles: rows already cover both triangles)
    if (!isDiag) {
        atomicAdd(&D8[j0 + cl0], sgn * colacc0);
        atomicAdd(&D8[j0 + cl1], sgn * colacc1);
    }

    // block reduce bsum (+ trace): wave shuffle then 4-way LDS
#pragma unroll
    for (int off = 32; off > 0; off >>= 1) bsum += __shfl_down(bsum, off);
    if (isTrace) {
#pragma unroll
        for (int off = 32; off > 0; off >>= 1) trsum += __shfl_down(trsum, off);
    }
    __syncthreads();               // E2 reads done; reuse smem as dred
    double* dred = (double*)smem;
    if (lane == 0) { dred[w] = bsum; dred[4 + w] = trsum; }
    __syncthreads();
    if (tid == 0) {
        double wgt = (sameHalf && !isDiag) ? 2.0 : 1.0;
        atomicAdd(&S[region], wgt * (dred[0] + dred[1] + dred[2] + dred[3]));
        if (isTrace) atomicAdd(&S[3], dred[4] + dred[5] + dred[6] + dred[7]);
    }
}

// ---------------- final scalar assembly ----------------
__global__ __launch_bounds__(256)
void final_kernel(const float* __restrict__ D8, const double* __restrict__ S,
                  float* __restrict__ out)
{
    __shared__ double buf[512];
    int tid = threadIdx.x;
    double sD = 0, sD2 = 0;
    for (int i = tid; i < 4096; i += 256) {
        double d = (double)D8[i] + (double)D8[i + 4096];
        sD += d; sD2 += d * d;
    }
    buf[tid] = sD; buf[256 + tid] = sD2;
    __syncthreads();
    for (int s = 128; s > 0; s >>= 1) {
        if (tid < s) { buf[tid] += buf[tid + s]; buf[256 + tid] += buf[256 + tid + s]; }
        __syncthreads();
    }
    if (tid == 0) {
        double n = (double)N_S, D = n * (n - 1.0);
        double xx = S[0] / D, yy = S[1] / D, xy = (S[2] - S[3]) / D;
        double mmd2 = xx - 2.0 * xy + yy;
        double sumd = buf[0], sumd2 = buf[256];
        double sumh = 2.0 * n + sumd;                    // hs_i = 2 + delta_i
        double sumhs2 = 4.0 * n + 4.0 * sumd + sumd2;
        double n3 = n * n * n, n4 = n3 * n;
        double var = 4.0 / n3 * sumhs2 - 4.0 / n4 * sumh * sumh + 1e-8;
        out[0] = (float)mmd2;
        out[1] = (float)var;
    }
}

extern "C" void kernel_launch(void* const* d_in, const int* in_sizes, int n_in,
                              void* d_out, int out_size, void* d_ws, size_t ws_size,
                              hipStream_t stream)
{
    const float* X   = (const float*)d_in[0];
    const float* Y   = (const float*)d_in[1];
    const float* W1  = (const float*)d_in[2];
    const float* b1  = (const float*)d_in[3];
    const float* W2  = (const float*)d_in[4];
    const float* b2  = (const float*)d_in[5];
    const float* W3  = (const float*)d_in[6];
    const float* b3  = (const float*)d_in[7];
    const float* W4  = (const float*)d_in[8];
    const float* b4  = (const float*)d_in[9];
    const float* ep  = (const float*)d_in[10];
    const float* sq  = (const float*)d_in[11];
    const float* sph = (const float*)d_in[12];
    float* out = (float*)d_out;

    char* ws = (char*)d_ws;
    float*  featsT = (float*)ws;                      // 52*8192*4 = 1703936
    float*  wOrg   = (float*)(ws + 1703936);          // 32768
    float*  D8     = (float*)(ws + 1736704);          // 32768
    double* S      = (double*)(ws + 1769472);         // 32 (Sxx, Syy, Sxy, trace)

    hipMemsetAsync(D8, 0, 32768 + 32, stream);

    mlp_kernel<<<128, 64, 0, stream>>>(X, Y, W1, b1, W2, b2, W3, b3, W4, b4,
                                       sq, featsT, wOrg);

    pair_kernel<<<2080, 256, 0, stream>>>(X, Y, featsT, wOrg, ep, sq, sph, D8, S);

    final_kernel<<<1, 256, 0, stream>>>(D8, S, out);
}

// Round 2
// 276.161 us; speedup vs baseline: 1.2300x; 1.0838x over previous
//
#include <hip/hip_runtime.h>
#include <math.h>

// DeepMMD, round 4: joint symmetric 8192x8192 pass, 128x128 tiles (2080 blocks).
//  - mlp: 8-way k-split (65536 threads), fp64 shuffle-allreduce, redundant tail
//  - pair phase A: register-prefetch of next K-block across a raw s_barrier
//    (keeps global loads in flight through the MFMA phase), setprio(1) on MFMA
//  - pair phase F: FB chunk-swizzle sigma(c)=c^(c>>4) -> 4-way conflict to 2-way
//  - reductions: row/col sums -> fp32 atomics on D8[8192]; S* fp64 atomics

#define N_S 4096
#define LOG2E 1.4426950408889634

typedef _Float16 v8h __attribute__((ext_vector_type(8)));
typedef float v16f __attribute__((ext_vector_type(16)));
typedef float v2f __attribute__((ext_vector_type(2)));

union U16 { uint4 u; v8h h; };

// ---------------- MLP (fp64 internals), 8-way k-split ----------------
// 256 blocks x 256 threads; thread group of 8 per sample row.
__global__ __launch_bounds__(256)
void mlp_kernel(const float* __restrict__ X, const float* __restrict__ Y,
                const float* __restrict__ W1, const float* __restrict__ b1,
                const float* __restrict__ W2, const float* __restrict__ b2,
                const float* __restrict__ W3, const float* __restrict__ b3,
                const float* __restrict__ W4, const float* __restrict__ b4,
                const float* __restrict__ sq,
                float* __restrict__ featsT, float* __restrict__ wOrg)
{
    // sW1 padded: group g at stride 330 doubles (2640B % 128 = 80 -> disjoint bank pairs)
    __shared__ double sW1[8 * 330];
    __shared__ double sW2[100], sW3[100], sW4[500];
    __shared__ double sb1[10], sb2[10], sb3[10], sb4[50];
    int tid = threadIdx.x;
    {   // tid = k row of W1 (256 rows)
        int kg = tid >> 5, kl = tid & 31;
#pragma unroll
        for (int j = 0; j < 10; ++j)
            sW1[kg * 330 + kl * 10 + j] = (double)W1[tid * 10 + j];
    }
    for (int i = tid; i < 100; i += 256) { sW2[i] = (double)W2[i]; sW3[i] = (double)W3[i]; }
    for (int i = tid; i < 500; i += 256) sW4[i] = (double)W4[i];
    if (tid < 10) { sb1[tid] = (double)b1[tid]; sb2[tid] = (double)b2[tid]; sb3[tid] = (double)b3[tid]; }
    if (tid < 50) sb4[tid] = (double)b4[tid];
    __syncthreads();

    int gt = blockIdx.x * 256 + tid;
    int r = gt >> 3, g = gt & 7;                 // row, k-group (8 lanes per row)
    const float* xr = (r < N_S) ? (X + (size_t)r * 256) : (Y + (size_t)(r - N_S) * 256);
    const float* xrg = xr + g * 32;
    const double* w1g = sW1 + g * 330;

    double z[10];
#pragma unroll
    for (int j = 0; j < 10; ++j) z[j] = 0.0;
    double nrm = 0.0;
    for (int k4 = 0; k4 < 32; k4 += 4) {
        float4 xv4 = *(const float4*)(xrg + k4);
        double xv[4] = {(double)xv4.x, (double)xv4.y, (double)xv4.z, (double)xv4.w};
#pragma unroll
        for (int u = 0; u < 4; ++u) {
            nrm += xv[u] * xv[u];
#pragma unroll
            for (int j = 0; j < 10; ++j) z[j] += xv[u] * w1g[(k4 + u) * 10 + j];
        }
    }
    // butterfly allreduce over the 8-lane group (identical results on all lanes)
#pragma unroll
    for (int off = 1; off < 8; off <<= 1) {
        nrm += __shfl_xor(nrm, off);
#pragma unroll
        for (int j = 0; j < 10; ++j) z[j] += __shfl_xor(z[j], off);
    }
#pragma unroll
    for (int j = 0; j < 10; ++j) z[j] += sb1[j];
#pragma unroll
    for (int j = 0; j < 10; ++j) z[j] = fmax(z[j], 0.0) + log1p(exp(-fabs(z[j])));

    double z2[10];
#pragma unroll
    for (int j = 0; j < 10; ++j) z2[j] = sb2[j];
#pragma unroll
    for (int k = 0; k < 10; ++k)
#pragma unroll
        for (int j = 0; j < 10; ++j) z2[j] += z[k] * sW2[k * 10 + j];
#pragma unroll
    for (int j = 0; j < 10; ++j) z2[j] = fmax(z2[j], 0.0) + log1p(exp(-fabs(z2[j])));

    double z3[10];
#pragma unroll
    for (int j = 0; j < 10; ++j) z3[j] = sb3[j];
#pragma unroll
    for (int k = 0; k < 10; ++k)
#pragma unroll
        for (int j = 0; j < 10; ++j) z3[j] += z2[k] * sW3[k * 10 + j];
#pragma unroll
    for (int j = 0; j < 10; ++j) z3[j] = fmax(z3[j], 0.0) + log1p(exp(-fabs(z3[j])));

    for (int j = 0; j < 50; ++j) {
        double f = sb4[j];
#pragma unroll
        for (int k = 0; k < 10; ++k) f += z3[k] * sW4[k * 50 + j];
        if ((j & 7) == g) featsT[(size_t)j * 8192 + r] = (float)f;
    }
    if (g == 2) featsT[(size_t)50 * 8192 + r] = 0.0f;
    if (g == 3) featsT[(size_t)51 * 8192 + r] = 0.0f;

    if (g == 0) {
        double sqv = (double)sq[0];
        double co = LOG2E / (sqv * sqv);
        wOrg[r] = (float)exp2(-nrm * co);
    }
}

// ---------------- helpers ----------------
__device__ __forceinline__ v8h ldfrag(const uint4* buf, int s, int g) {
    U16 t; t.u = buf[s * 8 + (g ^ (s & 7))];
    return t.h;
}

__device__ __forceinline__ void cvt_split(float4 f0, float4 f1, uint4* hi, uint4* lo) {
    U16 H, L;
    float fv[8] = {f0.x, f0.y, f0.z, f0.w, f1.x, f1.y, f1.z, f1.w};
#pragma unroll
    for (int u = 0; u < 8; ++u) {
        _Float16 h = (_Float16)fv[u];
        H.h[u] = h;
        L.h[u] = (_Float16)(fv[u] - (float)h);
    }
    *hi = H.u; *lo = L.u;
}

// ---------------- joint pairwise pass ----------------
__global__ __launch_bounds__(256, 2)
void pair_kernel(const float* __restrict__ X, const float* __restrict__ Y,
                 const float* __restrict__ featsT, const float* __restrict__ wOrg,
                 const float* __restrict__ ep, const float* __restrict__ sq,
                 const float* __restrict__ sph,
                 float* __restrict__ D8, double* __restrict__ S)
{
    // LDS union: phase F: FA[50][132] (26400) + FB[50][128] swizzled (25600) = 52000
    //            phase A: Ahi/Alo/Bhi/Blo uint4[1024] each = 65536
    //            epilogue: E2[128][128] f32 = 65536; dred 8 f64 (overlaid after sync)
    __shared__ __align__(16) char smem[65536];

    int tid = threadIdx.x;
    int lane = tid & 63, w = tid >> 6, wr = w >> 1, wc = w & 1;
    int tx = tid & 15, ty = tid >> 4;

    // upper-triangle tile decode
    int L = blockIdx.x, it = 0, span = 64;
    while (L >= span) { L -= span; --span; ++it; }
    int jt = it + L;

    bool sameHalf = (jt < 32) || (it >= 32);
    bool isDiag = (it == jt);
    bool isTrace = (jt == it + 32);
    int region = (jt < 32) ? 0 : ((it >= 32) ? 1 : 2);
    float sgn = sameHalf ? 1.0f : -1.0f;
    int i0 = it * 128, j0 = jt * 128;
    const float* aorg = (it < 32) ? X + (size_t)i0 * 256 : Y + (size_t)(i0 - N_S) * 256;
    const float* borg = (jt < 32) ? X + (size_t)j0 * 256 : Y + (size_t)(j0 - N_S) * 256;

    double epd = (double)ep[0];
    double eps = 1.0 / (1.0 + exp(-epd));
    double sqv = (double)sq[0], spv = (double)sph[0];
    float cf = (float)(LOG2E / (spv * spv));            // feature exponent scale
    float twoco = (float)(2.0 * LOG2E / (sqv * sqv));   // org dot exponent scale
    float epsv = (float)eps, ome = (float)(1.0 - eps);

    // prefetch buffer for phase-A staging (one full K-block: 16 float4)
    float4 R[16];
    auto loadregs = [&](int kb) {
#pragma unroll
        for (int step = 0; step < 4; ++step) {
            int rr = step * 32 + (tid >> 3), g8 = tid & 7;
            const float* pa = aorg + (size_t)rr * 256 + kb + g8 * 8;
            const float* pb = borg + (size_t)rr * 256 + kb + g8 * 8;
            R[step * 4 + 0] = *(const float4*)pa;
            R[step * 4 + 1] = *(const float4*)(pa + 4);
            R[step * 4 + 2] = *(const float4*)pb;
            R[step * 4 + 3] = *(const float4*)(pb + 4);
        }
    };

    // ---- phase F: exact fp32 feature distances (8x8 per thread, packed f32) ----
    float* FA = (float*)smem;
    float* FB = (float*)(smem + 26400);
    for (int idx = tid; idx < 1600; idx += 256) {    // 50 rows x 32 chunks
        int k = idx >> 5, c = idx & 31, cg = c * 4;
        *(float4*)&FA[k * 132 + cg] = *(const float4*)&featsT[(size_t)k * 8192 + i0 + cg];
        int cs = (c ^ (c >> 4)) * 4;                 // chunk swizzle
        *(float4*)&FB[k * 128 + cs] = *(const float4*)&featsT[(size_t)k * 8192 + j0 + cg];
    }
    loadregs(0);       // org K-block 0 in flight across all of phase F
    __syncthreads();

    v2f da2[8][4];
#pragma unroll
    for (int i = 0; i < 8; ++i)
#pragma unroll
        for (int j = 0; j < 4; ++j) { da2[i][j][0] = 0.0f; da2[i][j][1] = 0.0f; }

    int r0 = ty * 8, c0 = tx * 8;
    int c0r = 2 * tx, c1r = 2 * tx + 1;
    int fb0off = (c0r ^ (c0r >> 4)) * 4;
    int fb1off = (c1r ^ (c1r >> 4)) * 4;
    for (int k = 0; k < 50; ++k) {
        float4 a0 = *(const float4*)&FA[k * 132 + r0];
        float4 a1 = *(const float4*)&FA[k * 132 + r0 + 4];
        float4 b0 = *(const float4*)&FB[k * 128 + fb0off];
        float4 b1 = *(const float4*)&FB[k * 128 + fb1off];
        float av[8] = {a0.x, a0.y, a0.z, a0.w, a1.x, a1.y, a1.z, a1.w};
        v2f bv[4];
        bv[0][0] = b0.x; bv[0][1] = b0.y; bv[1][0] = b0.z; bv[1][1] = b0.w;
        bv[2][0] = b1.x; bv[2][1] = b1.y; bv[3][0] = b1.z; bv[3][1] = b1.w;
#pragma unroll
        for (int i = 0; i < 8; ++i) {
            v2f ai; ai[0] = av[i]; ai[1] = av[i];
#pragma unroll
            for (int j = 0; j < 4; ++j) {
                v2f t = ai - bv[j];          // v_pk_add_f32 (neg)
                da2[i][j] += t * t;          // v_pk_fma_f32
            }
        }
    }
    // d -> e2 (kept in registers through phase A)
#pragma unroll
    for (int i = 0; i < 8; ++i)
#pragma unroll
        for (int j = 0; j < 4; ++j) {
            da2[i][j][0] = exp2f(-da2[i][j][0] * cf);
            da2[i][j][1] = exp2f(-da2[i][j][1] * cf);
        }
    __syncthreads();   // FA/FB dead

    // ---- phase A: fp16-split MFMA org dot, reg-prefetch pipeline ----
    uint4* Ahi = (uint4*)smem;
    uint4* Alo = Ahi + 1024;
    uint4* Bhi = Ahi + 2048;
    uint4* Blo = Ahi + 3072;

    v16f acc00{}, acc01{}, acc10{}, acc11{};
    int rs0 = wr * 64 + (lane & 31), rs1 = rs0 + 32;
    int cs0 = wc * 64 + (lane & 31), cs1 = cs0 + 32;

    for (int kb = 0; kb < 256; kb += 64) {
        // cvt + LDS-write from the prefetched registers
#pragma unroll
        for (int step = 0; step < 4; ++step) {
            int rr = step * 32 + (tid >> 3), g8 = tid & 7;
            int pg = rr * 8 + (g8 ^ (rr & 7));          // XOR swizzle, conflict-free b128
            uint4 hi, lo;
            cvt_split(R[step * 4 + 0], R[step * 4 + 1], &hi, &lo);
            Ahi[pg] = hi; Alo[pg] = lo;
            cvt_split(R[step * 4 + 2], R[step * 4 + 3], &hi, &lo);
            Bhi[pg] = hi; Blo[pg] = lo;
        }
        __syncthreads();            // vmcnt naturally 0 here (R consumed); free drain
        if (kb < 192) loadregs(kb + 64);    // next K-block: in flight across MFMA phase
        __builtin_amdgcn_s_setprio(1);
#pragma unroll
        for (int ks = 0; ks < 4; ++ks) {
            int g = ks * 2 + (lane >> 5);
            v8h ah0 = ldfrag(Ahi, rs0, g), ah1 = ldfrag(Ahi, rs1, g);
            v8h al0 = ldfrag(Alo, rs0, g), al1 = ldfrag(Alo, rs1, g);
            v8h bh0 = ldfrag(Bhi, cs0, g), bh1 = ldfrag(Bhi, cs1, g);
            v8h bl0 = ldfrag(Blo, cs0, g), bl1 = ldfrag(Blo, cs1, g);
            acc00 = __builtin_amdgcn_mfma_f32_32x32x16_f16(al0, bh0, acc00, 0, 0, 0);
            acc00 = __builtin_amdgcn_mfma_f32_32x32x16_f16(ah0, bl0, acc00, 0, 0, 0);
            acc00 = __builtin_amdgcn_mfma_f32_32x32x16_f16(ah0, bh0, acc00, 0, 0, 0);
            acc01 = __builtin_amdgcn_mfma_f32_32x32x16_f16(al0, bh1, acc01, 0, 0, 0);
            acc01 = __builtin_amdgcn_mfma_f32_32x32x16_f16(ah0, bl1, acc01, 0, 0, 0);
            acc01 = __builtin_amdgcn_mfma_f32_32x32x16_f16(ah0, bh1, acc01, 0, 0, 0);
            acc10 = __builtin_amdgcn_mfma_f32_32x32x16_f16(al1, bh0, acc10, 0, 0, 0);
            acc10 = __builtin_amdgcn_mfma_f32_32x32x16_f16(ah1, bl0, acc10, 0, 0, 0);
            acc10 = __builtin_amdgcn_mfma_f32_32x32x16_f16(ah1, bh0, acc10, 0, 0, 0);
            acc11 = __builtin_amdgcn_mfma_f32_32x32x16_f16(al1, bh1, acc11, 0, 0, 0);
            acc11 = __builtin_amdgcn_mfma_f32_32x32x16_f16(ah1, bl1, acc11, 0, 0, 0);
            acc11 = __builtin_amdgcn_mfma_f32_32x32x16_f16(ah1, bh1, acc11, 0, 0, 0);
        }
        __builtin_amdgcn_s_setprio(0);
        // raw barrier: all ds_reads already consumed by MFMAs (lgkm drained),
        // no ds_writes pending -> semantically complete; keeps prefetch loads
        // in flight (a __syncthreads here would vmcnt(0)-drain them).
        __builtin_amdgcn_sched_barrier(0);
        __builtin_amdgcn_s_barrier();
        __builtin_amdgcn_sched_barrier(0);
    }

    // ---- epilogue: single full-tile pass, all waves ----
    float* E2 = (float*)smem;

    // write e2 (thread-tile layout) into full 128x128 LDS tile
#pragma unroll
    for (int i = 0; i < 8; ++i) {
        float4 v0 = make_float4(da2[i][0][0], da2[i][0][1], da2[i][1][0], da2[i][1][1]);
        float4 v1 = make_float4(da2[i][2][0], da2[i][2][1], da2[i][3][0], da2[i][3][1]);
        *(float4*)&E2[(r0 + i) * 128 + c0] = v0;
        *(float4*)&E2[(r0 + i) * 128 + c0 + 4] = v1;
    }
    __syncthreads();

    // each wave evaluates its own 4 accs in MFMA C-layout
    double bsum0 = 0.0, bsum1 = 0.0, trsum = 0.0;
    float colacc0 = 0.0f, colacc1 = 0.0f;
    int cl0 = wc * 64 + (lane & 31), cl1 = cl0 + 32;
    float wb0 = wOrg[j0 + cl0];
    float wb1 = wOrg[j0 + cl1];

    auto evalpair = [&](const v16f& aj0, const v16f& aj1, int rbase) {
        float4 wa4[4];
#pragma unroll
        for (int q = 0; q < 4; ++q)
            wa4[q] = *(const float4*)&wOrg[i0 + rbase + 4 * (lane >> 5) + 8 * q];
#pragma unroll
        for (int reg = 0; reg < 16; ++reg) {
            int rl = rbase + 4 * (lane >> 5) + (reg & 3) + 8 * (reg >> 2);
            float wa = ((const float*)&wa4[reg >> 2])[reg & 3];
            {
                float e2v = E2[rl * 128 + cl0];
                float kv = wa * wb0 * exp2f(aj0[reg] * twoco) * (ome * e2v + epsv);
                if (isDiag && rl == cl0) kv = 0.0f;
                if (isTrace && cl0 == rl) trsum += (double)kv;
                bsum0 += (double)kv;
                colacc0 += kv;
                E2[rl * 128 + cl0] = kv;
            }
            {
                float e2v = E2[rl * 128 + cl1];
                float kv = wa * wb1 * exp2f(aj1[reg] * twoco) * (ome * e2v + epsv);
                if (isDiag && rl == cl1) kv = 0.0f;
                if (isTrace && cl1 == rl) trsum += (double)kv;
                bsum1 += (double)kv;
                colacc1 += kv;
                E2[rl * 128 + cl1] = kv;
            }
        }
    };
    evalpair(acc00, acc01, wr * 64);
    evalpair(acc10, acc11, wr * 64 + 32);
    double bsum = bsum0 + bsum1;
    __syncthreads();

    // row sums: 2 threads per row, rotated start to spread banks
    {
        int row = tid >> 1, half = tid & 1;
        float s = 0.0f;
#pragma unroll
        for (int q = 0; q < 16; ++q) {
            int qq = (q + row) & 15;
            float4 v = *(const float4*)&E2[row * 128 + half * 64 + qq * 4];
            s += v.x + v.y + v.z + v.w;
        }
        s += __shfl_xor(s, 1);
        if (half == 0) atomicAdd(&D8[i0 + row], sgn * s);
    }

    // column sums (skip for diagonal tiles: rows already cover both triangles)
    if (!isDiag) {
        atomicAdd(&D8[j0 + cl0], sgn * colacc0);
        atomicAdd(&D8[j0 + cl1], sgn * colacc1);
    }

    // block reduce bsum (+ trace): wave shuffle then 4-way LDS
#pragma unroll
    for (int off = 32; off > 0; off >>= 1) bsum += __shfl_down(bsum, off);
    if (isTrace) {
#pragma unroll
        for (int off = 32; off > 0; off >>= 1) trsum += __shfl_down(trsum, off);
    }
    __syncthreads();               // E2 reads done; reuse smem as dred
    double* dred = (double*)smem;
    if (lane == 0) { dred[w] = bsum; dred[4 + w] = trsum; }
    __syncthreads();
    if (tid == 0) {
        double wgt = (sameHalf && !isDiag) ? 2.0 : 1.0;
        atomicAdd(&S[region], wgt * (dred[0] + dred[1] + dred[2] + dred[3]));
        if (isTrace) atomicAdd(&S[3], dred[4] + dred[5] + dred[6] + dred[7]);
    }
}

// ---------------- final scalar assembly ----------------
__global__ __launch_bounds__(256)
void final_kernel(const float* __restrict__ D8, const double* __restrict__ S,
                  float* __restrict__ out)
{
    __shared__ double buf[512];
    int tid = threadIdx.x;
    double sD = 0, sD2 = 0;
    for (int i = tid; i < 4096; i += 256) {
        double d = (double)D8[i] + (double)D8[i + 4096];
        sD += d; sD2 += d * d;
    }
    buf[tid] = sD; buf[256 + tid] = sD2;
    __syncthreads();
    for (int s = 128; s > 0; s >>= 1) {
        if (tid < s) { buf[tid] += buf[tid + s]; buf[256 + tid] += buf[256 + tid + s]; }
        __syncthreads();
    }
    if (tid == 0) {
        double n = (double)N_S, D = n * (n - 1.0);
        double xx = S[0] / D, yy = S[1] / D, xy = (S[2] - S[3]) / D;
        double mmd2 = xx - 2.0 * xy + yy;
        double sumd = buf[0], sumd2 = buf[256];
        double sumh = 2.0 * n + sumd;                    // hs_i = 2 + delta_i
        double sumhs2 = 4.0 * n + 4.0 * sumd + sumd2;
        double n3 = n * n * n, n4 = n3 * n;
        double var = 4.0 / n3 * sumhs2 - 4.0 / n4 * sumh * sumh + 1e-8;
        out[0] = (float)mmd2;
        out[1] = (float)var;
    }
}

extern "C" void kernel_launch(void* const* d_in, const int* in_sizes, int n_in,
                              void* d_out, int out_size, void* d_ws, size_t ws_size,
                              hipStream_t stream)
{
    const float* X   = (const float*)d_in[0];
    const float* Y   = (const float*)d_in[1];
    const float* W1  = (const float*)d_in[2];
    const float* b1  = (const float*)d_in[3];
    const float* W2  = (const float*)d_in[4];
    const float* b2  = (const float*)d_in[5];
    const float* W3  = (const float*)d_in[6];
    const float* b3  = (const float*)d_in[7];
    const float* W4  = (const float*)d_in[8];
    const float* b4  = (const float*)d_in[9];
    const float* ep  = (const float*)d_in[10];
    const float* sq  = (const float*)d_in[11];
    const float* sph = (const float*)d_in[12];
    float* out = (float*)d_out;

    char* ws = (char*)d_ws;
    float*  featsT = (float*)ws;                      // 52*8192*4 = 1703936
    float*  wOrg   = (float*)(ws + 1703936);          // 32768
    float*  D8     = (float*)(ws + 1736704);          // 32768
    double* S      = (double*)(ws + 1769472);         // 32 (Sxx, Syy, Sxy, trace)

    hipMemsetAsync(D8, 0, 32768 + 32, stream);

    mlp_kernel<<<256, 256, 0, stream>>>(X, Y, W1, b1, W2, b2, W3, b3, W4, b4,
                                        sq, featsT, wOrg);

    pair_kernel<<<2080, 256, 0, stream>>>(X, Y, featsT, wOrg, ep, sq, sph, D8, S);

    final_kernel<<<1, 256, 0, stream>>>(D8, S, out);
}